// Round 2
// baseline (455.298 us; speedup 1.0000x reference)
//
#include <hip/hip_runtime.h>

typedef __attribute__((ext_vector_type(8))) short short8;
typedef __attribute__((ext_vector_type(4))) float f32x4;

#define MFMA_BF16(A,B,C) __builtin_amdgcn_mfma_f32_16x16x32_bf16((A),(B),(C),0,0,0)

__device__ __forceinline__ unsigned short f2bu(float f) {
  unsigned int u = __float_as_uint(f);
  u += 0x7fffu + ((u >> 16) & 1u);   // round-to-nearest-even
  return (unsigned short)(u >> 16);
}

// ---------------- transpose 1024x1024 f32 -> bf16: wt[n][k] = w[k][n] ----------------
__global__ __launch_bounds__(256) void transpose_cvt_kernel(const float* __restrict__ w,
                                                            unsigned short* __restrict__ wt) {
  __shared__ float t[32][33];
  const int bx = blockIdx.x * 32;  // k block
  const int by = blockIdx.y * 32;  // n block
  const int tx = threadIdx.x & 31, ty = threadIdx.x >> 5;
  for (int j = 0; j < 4; ++j)
    t[ty + 8 * j][tx] = w[(size_t)(bx + ty + 8 * j) * 1024 + by + tx];
  __syncthreads();
  for (int j = 0; j < 4; ++j)
    wt[(size_t)(by + ty + 8 * j) * 1024 + bx + tx] = f2bu(t[tx][ty + 8 * j]);
}

// ---------------- C[4096][1024] = A[4096][1024] @ W + bias ----------------
// A row-major (f32 if A_F32, else bf16; f32 is converted to bf16 while staging
// to LDS). Wt bf16 with row n = column n of W (B-fragments 8-contiguous in K).
// Tile 128(M) x 64(N), 4 waves over M, BK=32.
template <int A_F32, int OUT_F32>
__global__ __launch_bounds__(256) void gemm_bias_kernel(
    const void* __restrict__ Ap, const unsigned short* __restrict__ Wt,
    const float* __restrict__ bias, void* __restrict__ Cout) {
  __shared__ unsigned short a_lds[128][40];
  __shared__ unsigned short b_lds[64][40];
  const int M0 = blockIdx.x * 128, N0 = blockIdx.y * 64;
  const int tid = threadIdx.x, lane = tid & 63, wid = tid >> 6;
  const int lr = lane & 15, lg = lane >> 4;
  f32x4 acc[2][4];
  for (int i = 0; i < 2; ++i)
    for (int j = 0; j < 4; ++j) acc[i][j] = (f32x4){0.f, 0.f, 0.f, 0.f};

  for (int k0 = 0; k0 < 1024; k0 += 32) {
    if (A_F32) {
      const float* A = (const float*)Ap;
#pragma unroll
      for (int it = 0; it < 4; ++it) {
        int c = tid + it * 256;
        int row = c >> 3, col4 = (c & 7) * 4;
        float4 v = *reinterpret_cast<const float4*>(&A[(size_t)(M0 + row) * 1024 + k0 + col4]);
        ushort4 o;
        o.x = f2bu(v.x); o.y = f2bu(v.y); o.z = f2bu(v.z); o.w = f2bu(v.w);
        *reinterpret_cast<ushort4*>(&a_lds[row][col4]) = o;
      }
    } else {
      const unsigned short* A = (const unsigned short*)Ap;
#pragma unroll
      for (int it = 0; it < 2; ++it) {
        int c = tid + it * 256;
        int row = c >> 2, col8 = (c & 3) * 8;
        *reinterpret_cast<short8*>(&a_lds[row][col8]) =
            *reinterpret_cast<const short8*>(&A[(size_t)(M0 + row) * 1024 + k0 + col8]);
      }
    }
    {
      int row = tid >> 2, col8 = (tid & 3) * 8;
      *reinterpret_cast<short8*>(&b_lds[row][col8]) =
          *reinterpret_cast<const short8*>(&Wt[(size_t)(N0 + row) * 1024 + k0 + col8]);
    }
    __syncthreads();
    short8 a0 = *reinterpret_cast<const short8*>(&a_lds[wid * 32 + lr][lg * 8]);
    short8 a1 = *reinterpret_cast<const short8*>(&a_lds[wid * 32 + 16 + lr][lg * 8]);
#pragma unroll
    for (int nt = 0; nt < 4; ++nt) {
      short8 bfr = *reinterpret_cast<const short8*>(&b_lds[nt * 16 + lr][lg * 8]);
      acc[0][nt] = MFMA_BF16(a0, bfr, acc[0][nt]);
      acc[1][nt] = MFMA_BF16(a1, bfr, acc[1][nt]);
    }
    __syncthreads();
  }
#pragma unroll
  for (int mt = 0; mt < 2; ++mt)
#pragma unroll
    for (int nt = 0; nt < 4; ++nt)
#pragma unroll
      for (int r = 0; r < 4; ++r) {
        int grow = M0 + wid * 32 + mt * 16 + lg * 4 + r;
        int gcol = N0 + nt * 16 + lr;
        float vv = acc[mt][nt][r] + bias[gcol];
        if (OUT_F32)
          reinterpret_cast<float*>(Cout)[(size_t)grow * 1024 + gcol] = vv;
        else
          reinterpret_cast<unsigned short*>(Cout)[(size_t)grow * 1024 + gcol] = f2bu(vv);
      }
}

// ---------------- fused attention ----------------
// One block = one (b, h, q-tile of 64). 4 waves, wave handles 16 q-rows.
// Pass 1: online row max/sum over all K. Pass 2: recompute logits, write
// softmax weights (f32) to d_out, accumulate PV via MFMA. Writes attention
// output bf16 directly in [B,S,H*64] concat layout.
__global__ __launch_bounds__(256) void attn_kernel(
    const unsigned short* __restrict__ Qp, const unsigned short* __restrict__ Kp,
    const unsigned short* __restrict__ Vp, float* __restrict__ attnw,
    unsigned short* __restrict__ attnc) {
  const int S = 2048, Dm = 1024;
  __shared__ unsigned short k_lds[64][72];
  __shared__ unsigned short vt_lds[64][72];
  __shared__ unsigned short w_lds[4][16][72];
  const int bid = blockIdx.x;
  const int qt = bid & 31, h = (bid >> 5) & 15, b = bid >> 9;
  const int tid = threadIdx.x, lane = tid & 63, wid = tid >> 6;
  const int lr = lane & 15, lg = lane >> 4;
  const int q0 = qt * 64;
  const float scale = 0.125f;

  const unsigned short* qrow = Qp + (size_t)(b * S + q0 + wid * 16 + lr) * Dm + h * 64;
  short8 aq0 = *reinterpret_cast<const short8*>(&qrow[lg * 8]);
  short8 aq1 = *reinterpret_cast<const short8*>(&qrow[32 + lg * 8]);

  float m[4], l[4];
  for (int r = 0; r < 4; ++r) { m[r] = -1e30f; l[r] = 0.f; }

  const size_t kvbase = (size_t)(b * S) * Dm + h * 64;

  // ---- pass 1: row stats ----
  for (int kt = 0; kt < 32; ++kt) {
    int k0 = kt * 64;
    for (int c = tid; c < 512; c += 256) {
      int row = c >> 3, col8 = (c & 7) * 8;
      *reinterpret_cast<short8*>(&k_lds[row][col8]) =
          *reinterpret_cast<const short8*>(&Kp[kvbase + (size_t)(k0 + row) * Dm + col8]);
    }
    __syncthreads();
    f32x4 lacc[4];
#pragma unroll
    for (int nt = 0; nt < 4; ++nt) {
      short8 kb0 = *reinterpret_cast<const short8*>(&k_lds[nt * 16 + lr][lg * 8]);
      short8 kb1 = *reinterpret_cast<const short8*>(&k_lds[nt * 16 + lr][32 + lg * 8]);
      f32x4 z = (f32x4){0.f, 0.f, 0.f, 0.f};
      z = MFMA_BF16(aq0, kb0, z);
      z = MFMA_BF16(aq1, kb1, z);
      lacc[nt] = z;
    }
#pragma unroll
    for (int r = 0; r < 4; ++r) {
      float tmax = fmaxf(fmaxf(lacc[0][r], lacc[1][r]), fmaxf(lacc[2][r], lacc[3][r])) * scale;
      tmax = fmaxf(tmax, __shfl_xor(tmax, 1));
      tmax = fmaxf(tmax, __shfl_xor(tmax, 2));
      tmax = fmaxf(tmax, __shfl_xor(tmax, 4));
      tmax = fmaxf(tmax, __shfl_xor(tmax, 8));
      float mnew = fmaxf(m[r], tmax);
      float s = 0.f;
#pragma unroll
      for (int nt = 0; nt < 4; ++nt) s += __expf(lacc[nt][r] * scale - mnew);
      s += __shfl_xor(s, 1);
      s += __shfl_xor(s, 2);
      s += __shfl_xor(s, 4);
      s += __shfl_xor(s, 8);
      l[r] = l[r] * __expf(m[r] - mnew) + s;
      m[r] = mnew;
    }
    __syncthreads();
  }
  float invl[4];
  for (int r = 0; r < 4; ++r) invl[r] = 1.f / l[r];

  f32x4 oacc[4];
  for (int nt = 0; nt < 4; ++nt) oacc[nt] = (f32x4){0.f, 0.f, 0.f, 0.f};

  // ---- pass 2: weights out + PV ----
  for (int kt = 0; kt < 32; ++kt) {
    int k0 = kt * 64;
    for (int c = tid; c < 1024; c += 256) {
      if (c < 512) {
        int row = c >> 3, col8 = (c & 7) * 8;
        *reinterpret_cast<short8*>(&k_lds[row][col8]) =
            *reinterpret_cast<const short8*>(&Kp[kvbase + (size_t)(k0 + row) * Dm + col8]);
      } else {
        int cc = c - 512, key = cc >> 3, d0 = (cc & 7) * 8;
        short8 vv = *reinterpret_cast<const short8*>(&Vp[kvbase + (size_t)(k0 + key) * Dm + d0]);
#pragma unroll
        for (int j = 0; j < 8; ++j)
          vt_lds[d0 + j][key] = ((const unsigned short*)&vv)[j];
      }
    }
    __syncthreads();
    f32x4 lacc[4];
#pragma unroll
    for (int nt = 0; nt < 4; ++nt) {
      short8 kb0 = *reinterpret_cast<const short8*>(&k_lds[nt * 16 + lr][lg * 8]);
      short8 kb1 = *reinterpret_cast<const short8*>(&k_lds[nt * 16 + lr][32 + lg * 8]);
      f32x4 z = (f32x4){0.f, 0.f, 0.f, 0.f};
      z = MFMA_BF16(aq0, kb0, z);
      z = MFMA_BF16(aq1, kb1, z);
      lacc[nt] = z;
    }
#pragma unroll
    for (int nt = 0; nt < 4; ++nt) {
#pragma unroll
      for (int r = 0; r < 4; ++r) {
        float wv = __expf(lacc[nt][r] * scale - m[r]) * invl[r];
        size_t qrow_g = (size_t)((b * 16 + h) * 2048 + q0 + wid * 16 + lg * 4 + r);
        attnw[qrow_g * 2048 + k0 + nt * 16 + lr] = wv;
        w_lds[wid][lg * 4 + r][nt * 16 + lr] = f2bu(wv);
      }
    }
    __syncthreads();  // hazard hardening: ensure w_lds writes land before b128 reads
    short8 wa0 = *reinterpret_cast<const short8*>(&w_lds[wid][lr][lg * 8]);
    short8 wa1 = *reinterpret_cast<const short8*>(&w_lds[wid][lr][32 + lg * 8]);
#pragma unroll
    for (int nt = 0; nt < 4; ++nt) {
      short8 vb0 = *reinterpret_cast<const short8*>(&vt_lds[nt * 16 + lr][lg * 8]);
      short8 vb1 = *reinterpret_cast<const short8*>(&vt_lds[nt * 16 + lr][32 + lg * 8]);
      oacc[nt] = MFMA_BF16(wa0, vb0, oacc[nt]);
      oacc[nt] = MFMA_BF16(wa1, vb1, oacc[nt]);
    }
    __syncthreads();
  }
#pragma unroll
  for (int nt = 0; nt < 4; ++nt)
#pragma unroll
    for (int r = 0; r < 4; ++r) {
      int srow = q0 + wid * 16 + lg * 4 + r;
      attnc[(size_t)(b * S + srow) * Dm + h * 64 + nt * 16 + lr] = f2bu(oacc[nt][r]);
    }
}

extern "C" void kernel_launch(void* const* d_in, const int* in_sizes, int n_in,
                              void* d_out, int out_size, void* d_ws, size_t ws_size,
                              hipStream_t stream) {
  const float* q = (const float*)d_in[0];
  const float* k = (const float*)d_in[1];
  const float* v = (const float*)d_in[2];
  const float* w_q = (const float*)d_in[3];
  const float* b_q = (const float*)d_in[4];
  const float* w_k = (const float*)d_in[5];
  const float* b_k = (const float*)d_in[6];
  const float* w_v = (const float*)d_in[7];
  const float* b_v = (const float*)d_in[8];
  const float* w_o = (const float*)d_in[9];
  const float* b_o = (const float*)d_in[10];

  // ws layout (bf16 elements), 40 MiB total:
  //   wqt,wkt,wvt,wot [1024x1024] | Qp,Kp,Vp [4096x1024] | attnc [4096x1024]
  unsigned short* ws = (unsigned short*)d_ws;
  unsigned short* wqt = ws;
  unsigned short* wkt = wqt + 1048576;
  unsigned short* wvt = wkt + 1048576;
  unsigned short* wot = wvt + 1048576;
  unsigned short* Qp = ws + 4194304;
  unsigned short* Kp = Qp + 4194304;
  unsigned short* Vp = Kp + 4194304;
  unsigned short* attnc = Vp + 4194304;

  float* outO = (float*)d_out;
  float* attnw = outO + 4194304;  // [2,16,2048,2048]

  transpose_cvt_kernel<<<dim3(32, 32), 256, 0, stream>>>(w_q, wqt);
  transpose_cvt_kernel<<<dim3(32, 32), 256, 0, stream>>>(w_k, wkt);
  transpose_cvt_kernel<<<dim3(32, 32), 256, 0, stream>>>(w_v, wvt);
  transpose_cvt_kernel<<<dim3(32, 32), 256, 0, stream>>>(w_o, wot);

  gemm_bias_kernel<1, 0><<<dim3(32, 16), 256, 0, stream>>>(q, wqt, b_q, (void*)Qp);
  gemm_bias_kernel<1, 0><<<dim3(32, 16), 256, 0, stream>>>(k, wkt, b_k, (void*)Kp);
  gemm_bias_kernel<1, 0><<<dim3(32, 16), 256, 0, stream>>>(v, wvt, b_v, (void*)Vp);

  attn_kernel<<<1024, 256, 0, stream>>>(Qp, Kp, Vp, attnw, attnc);

  gemm_bias_kernel<0, 1><<<dim3(32, 16), 256, 0, stream>>>(attnc, wot, b_o, d_out);
}